// Round 8
// baseline (380.146 us; speedup 1.0000x reference)
//
#include <hip/hip_runtime.h>

typedef unsigned short u16;
typedef __attribute__((ext_vector_type(8))) short short8;
typedef __attribute__((ext_vector_type(4))) float f32x4;

#define A_ 4
#define T_ 128
#define B_ 256
#define OBS_ 128
#define H_ 128
#define G_ 384
#define ACT_ 8

__device__ __forceinline__ u16 f2b(float x) {
    unsigned int u = __float_as_uint(x);
    u = (u + 0x7fffu + ((u >> 16) & 1u)) >> 16;
    return (u16)u;
}
__device__ __forceinline__ u16 f2bc(float x) {  // cheap RN (ties up) for hot loop
    return (u16)((__float_as_uint(x) + 0x8000u) >> 16);
}
__device__ __forceinline__ float b2f(u16 h) {
    return __uint_as_float(((unsigned int)h) << 16);
}
__device__ __forceinline__ float fexp2_(float x) { return __builtin_amdgcn_exp2f(x); }
__device__ __forceinline__ float frcp_(float x) { return __builtin_amdgcn_rcpf(x); }
__device__ __forceinline__ float sigmoidf_(float x) {
    return frcp_(1.0f + fexp2_(-1.4426950408889634f * x));
}
__device__ __forceinline__ float tanhf_(float x) {
    return 1.0f - 2.0f * frcp_(1.0f + fexp2_(2.8853900817779268f * x));
}
__device__ __forceinline__ f32x4 mfma16(short8 a, short8 b, f32x4 c) {
    return __builtin_amdgcn_mfma_f32_16x16x32_bf16(a, b, c, 0, 0, 0);
}

// lgkm-only barrier (proven correct r5-r7) — used in embed/heads
__device__ __forceinline__ void bar_lds() {
    __asm__ volatile("" ::: "memory");
    __builtin_amdgcn_s_waitcnt(0xC07F);
    __builtin_amdgcn_s_barrier();
    __asm__ volatile("" ::: "memory");
}

// ---------------- K0: weight transpose/convert + std output ----------------
__global__ void k_prep(const float* __restrict__ We, const float* __restrict__ Wi,
                       const float* __restrict__ Wh, const float* __restrict__ Wa1,
                       const float* __restrict__ Wc1, const float* __restrict__ Wa2,
                       const float* __restrict__ Wc2, const float* __restrict__ log_std,
                       u16* __restrict__ weT, u16* __restrict__ wiT, u16* __restrict__ whT,
                       u16* __restrict__ wa1T, u16* __restrict__ wc1T, u16* __restrict__ h2T,
                       float* __restrict__ std_out) {
    const int PER_A = 149504;
    int idx = blockIdx.x * 256 + threadIdx.x;
    const int total = 4 * PER_A;
    if (idx < total) {
        int a = idx / PER_A;
        int i = idx % PER_A;
        if (i < 16384) {
            int h = i >> 7, o = i & 127;
            weT[a * 16384 + i] = f2b(We[a * 16384 + o * 128 + h]);
        } else if (i < 16384 + 49152) {
            int j = i - 16384; int g = j >> 7, k = j & 127;
            wiT[a * 49152 + j] = f2b(Wi[a * 49152 + k * 384 + g]);
        } else if (i < 16384 + 2 * 49152) {
            int j = i - 16384 - 49152; int g = j >> 7, k = j & 127;
            whT[a * 49152 + j] = f2b(Wh[a * 49152 + k * 384 + g]);
        } else if (i < 2 * 16384 + 2 * 49152) {
            int j = i - 16384 - 2 * 49152; int h2 = j >> 7, k = j & 127;
            wa1T[a * 16384 + j] = f2b(Wa1[a * 16384 + k * 128 + h2]);
        } else if (i < 3 * 16384 + 2 * 49152) {
            int j = i - 2 * 16384 - 2 * 49152; int h2 = j >> 7, k = j & 127;
            wc1T[a * 16384 + j] = f2b(Wc1[a * 16384 + k * 128 + h2]);
        } else {
            int j = i - 3 * 16384 - 2 * 49152; int row = j >> 7, k = j & 127;
            float v = 0.f;
            if (row < 8) v = Wa2[a * 1024 + k * 8 + row];
            else if (row == 8) v = Wc2[a * 128 + k];
            h2T[a * 2048 + j] = f2b(v);
        }
    } else if (idx < total + 32) {
        int i = idx - total;
        std_out[i] = __expf(log_std[i]);
    }
}

// ---------------- K1: fused emb/xi, weight-stationary (r3 structure) -------
__global__ __launch_bounds__(512) void k_embed_xi(
    const float* __restrict__ obs, const float* __restrict__ be, const float* __restrict__ bi,
    const u16* __restrict__ weT, const u16* __restrict__ wiT, u16* __restrict__ xi_ws) {
    __shared__ __align__(16) u16 obsl[16][136];
    __shared__ __align__(16) u16 elds[16][136];
    const int a = blockIdx.y, t = blockIdx.x;
    const int wid = threadIdx.x >> 6, lane = threadIdx.x & 63;
    const int m = lane & 15, quad = lane >> 4;
    const int srow = threadIdx.x >> 5, schunk = threadIdx.x & 31;

    short8 we[4], wi[3][4];
    {
        const u16* p = weT + a * 16384 + (wid * 16 + m) * 128 + quad * 8;
#pragma unroll
        for (int ks = 0; ks < 4; ++ks) we[ks] = *(const short8*)(p + ks * 32);
#pragma unroll
        for (int g = 0; g < 3; ++g) {
            const u16* q = wiT + a * 49152 + (g * 128 + wid * 16 + m) * 128 + quad * 8;
#pragma unroll
            for (int ks = 0; ks < 4; ++ks) wi[g][ks] = *(const short8*)(q + ks * 32);
        }
    }
    const float bee = be[a * H_ + wid * 16 + m];
    float big[3];
#pragma unroll
    for (int g = 0; g < 3; ++g) big[g] = bi[a * G_ + g * 128 + wid * 16 + m];

    const float* obsrow = obs + ((size_t)(a * T_ + t) * B_ + srow) * OBS_ + schunk * 4;
    float4 pf = *(const float4*)(obsrow);
    ushort4* xi4 = (ushort4*)xi_ws;

    for (int it = 0; it < 16; ++it) {
        ushort4 ob;
        ob.x = f2b(pf.x); ob.y = f2b(pf.y); ob.z = f2b(pf.z); ob.w = f2b(pf.w);
        *(ushort4*)&obsl[srow][schunk * 4] = ob;
        bar_lds();
        if (it + 1 < 16) pf = *(const float4*)(obsrow + (size_t)(it + 1) * 2048);

        short8 af[4];
#pragma unroll
        for (int ks = 0; ks < 4; ++ks)
            af[ks] = *(const short8*)&obsl[m][ks * 32 + quad * 8];
        f32x4 acc = f32x4{0.f, 0.f, 0.f, 0.f};
#pragma unroll
        for (int ks = 0; ks < 4; ++ks) acc = mfma16(af[ks], we[ks], acc);
#pragma unroll
        for (int r = 0; r < 4; ++r)
            elds[quad * 4 + r][wid * 16 + m] = f2b(tanhf_(acc[r] + bee));
        bar_lds();

        short8 ef[4];
#pragma unroll
        for (int ks = 0; ks < 4; ++ks)
            ef[ks] = *(const short8*)&elds[m][ks * 32 + quad * 8];
        f32x4 xa[3];
#pragma unroll
        for (int g = 0; g < 3; ++g) xa[g] = f32x4{0.f, 0.f, 0.f, 0.f};
#pragma unroll
        for (int ks = 0; ks < 4; ++ks)
#pragma unroll
            for (int g = 0; g < 3; ++g) xa[g] = mfma16(ef[ks], wi[g][ks], xa[g]);

        const size_t base = ((size_t)(a * 16 + it) * T_ + t) * 1536;
#pragma unroll
        for (int g = 0; g < 3; ++g) {
            ushort4 pk;
            pk.x = f2b(xa[g][0] + big[g]);
            pk.y = f2b(xa[g][1] + big[g]);
            pk.z = f2b(xa[g][2] + big[g]);
            pk.w = f2b(xa[g][3] + big[g]);
            xi4[base + (size_t)(wid * 3 + g) * 64 + lane] = pk;
        }
    }
}

// ---------------- K2: GRU scan, 2 independent tiles per wave ---------------
// grid (8,4) x 512 thr = 32 blocks. Block owns btiles {2p,2p+1} of agent a;
// wave wid owns h-cols [16wid,16wid+16) for BOTH tiles. One __syncthreads per
// step; streams A/B are fully independent -> in-wave ILP hides ds_read/MFMA/
// transcendental latency that phase-locked waves cannot (r3-r7 evidence).
// Wh registers shared across tiles (same agent).
__global__ __launch_bounds__(512) void k_scan2(
    const float* __restrict__ hstate, const u16* __restrict__ xi_ws,
    const u16* __restrict__ whT, const float* __restrict__ bhn,
    const int* __restrict__ done, u16* __restrict__ ys_ws, float* __restrict__ hT_out) {
    __shared__ __align__(16) u16 hlds[2][2][16][136];  // [tile][buf][row][col]
    const int a = blockIdx.y, p = blockIdx.x;
    const int wid = threadIdx.x >> 6, lane = threadIdx.x & 63;
    const int m = lane & 15, quad = lane >> 4;
    const int col = 16 * wid + m;
    const int bA = (2 * p) * 16, bB = (2 * p + 1) * 16;

    short8 wh[3][4];
    const u16* whTa = whT + a * 49152;
#pragma unroll
    for (int g = 0; g < 3; ++g) {
        const u16* pp = whTa + (g * 128 + col) * 128 + quad * 8;
#pragma unroll
        for (int ks = 0; ks < 4; ++ks) wh[g][ks] = *(const short8*)(pp + ks * 32);
    }

    float hmA[4], hmB[4]; u16 hbA[4], hbB[4];
#pragma unroll
    for (int r = 0; r < 4; ++r) {
        float vA = hstate[((size_t)a * B_ + bA + quad * 4 + r) * H_ + col];
        float vB = hstate[((size_t)a * B_ + bB + quad * 4 + r) * H_ + col];
        hmA[r] = vA; hbA[r] = f2b(vA);
        hmB[r] = vB; hbB[r] = f2b(vB);
    }
    const float bh = bhn[a * H_ + col];

    const ushort4* xi4 = (const ushort4*)xi_ws;
    const size_t xibA = ((size_t)(a * 16 + 2 * p) * T_) * 1536 + wid * 192 + lane;
    const size_t xibB = ((size_t)(a * 16 + 2 * p + 1) * T_) * 1536 + wid * 192 + lane;
    const int* dbA = done + (size_t)a * T_ * B_ + bA + quad * 4;
    const int* dbB = done + (size_t)a * T_ * B_ + bB + quad * 4;

    ushort4 pA0 = xi4[xibA], pA1 = xi4[xibA + 64], pA2 = xi4[xibA + 128];
    ushort4 pB0 = xi4[xibB], pB1 = xi4[xibB + 64], pB2 = xi4[xibB + 128];
    int dA0 = dbA[0], dA1 = dbA[1], dA2 = dbA[2], dA3 = dbA[3];
    int dB0 = dbB[0], dB1 = dbB[1], dB2 = dbB[2], dB3 = dbB[3];

    for (int t = 0; t < T_; ++t) {
        const int buf = t & 1;
        u16 (*hlA)[136] = hlds[0][buf];
        u16 (*hlB)[136] = hlds[1][buf];
        if (dA0) { hmA[0] = 0.f; hbA[0] = 0; }
        if (dA1) { hmA[1] = 0.f; hbA[1] = 0; }
        if (dA2) { hmA[2] = 0.f; hbA[2] = 0; }
        if (dA3) { hmA[3] = 0.f; hbA[3] = 0; }
        if (dB0) { hmB[0] = 0.f; hbB[0] = 0; }
        if (dB1) { hmB[1] = 0.f; hbB[1] = 0; }
        if (dB2) { hmB[2] = 0.f; hbB[2] = 0; }
        if (dB3) { hmB[3] = 0.f; hbB[3] = 0; }
        hlA[quad * 4 + 0][col] = hbA[0];
        hlB[quad * 4 + 0][col] = hbB[0];
        hlA[quad * 4 + 1][col] = hbA[1];
        hlB[quad * 4 + 1][col] = hbB[1];
        hlA[quad * 4 + 2][col] = hbA[2];
        hlB[quad * 4 + 2][col] = hbB[2];
        hlA[quad * 4 + 3][col] = hbA[3];
        hlB[quad * 4 + 3][col] = hbB[3];
        __syncthreads();

        float xrA[4], xzA[4], xnA[4], xrB[4], xzB[4], xnB[4];
        xrA[0] = b2f(pA0.x); xrA[1] = b2f(pA0.y); xrA[2] = b2f(pA0.z); xrA[3] = b2f(pA0.w);
        xzA[0] = b2f(pA1.x); xzA[1] = b2f(pA1.y); xzA[2] = b2f(pA1.z); xzA[3] = b2f(pA1.w);
        xnA[0] = b2f(pA2.x); xnA[1] = b2f(pA2.y); xnA[2] = b2f(pA2.z); xnA[3] = b2f(pA2.w);
        xrB[0] = b2f(pB0.x); xrB[1] = b2f(pB0.y); xrB[2] = b2f(pB0.z); xrB[3] = b2f(pB0.w);
        xzB[0] = b2f(pB1.x); xzB[1] = b2f(pB1.y); xzB[2] = b2f(pB1.z); xzB[3] = b2f(pB1.w);
        xnB[0] = b2f(pB2.x); xnB[1] = b2f(pB2.y); xnB[2] = b2f(pB2.z); xnB[3] = b2f(pB2.w);
        if (t + 1 < T_) {
            const size_t nA = xibA + (size_t)(t + 1) * 1536;
            const size_t nB = xibB + (size_t)(t + 1) * 1536;
            pA0 = xi4[nA]; pA1 = xi4[nA + 64]; pA2 = xi4[nA + 128];
            pB0 = xi4[nB]; pB1 = xi4[nB + 64]; pB2 = xi4[nB + 128];
            const int* dpA = dbA + (size_t)(t + 1) * B_;
            const int* dpB = dbB + (size_t)(t + 1) * B_;
            dA0 = dpA[0]; dA1 = dpA[1]; dA2 = dpA[2]; dA3 = dpA[3];
            dB0 = dpB[0]; dB1 = dpB[1]; dB2 = dpB[2]; dB3 = dpB[3];
        }

        short8 afA[4], afB[4];
#pragma unroll
        for (int ks = 0; ks < 4; ++ks) {
            afA[ks] = *(const short8*)&hlA[m][ks * 32 + quad * 8];
            afB[ks] = *(const short8*)&hlB[m][ks * 32 + quad * 8];
        }

        f32x4 arA = f32x4{0.f, 0.f, 0.f, 0.f}, azA = arA, anA = arA;
        f32x4 arB = f32x4{0.f, 0.f, 0.f, 0.f}, azB = arB, anB = arB;
#pragma unroll
        for (int ks = 0; ks < 4; ++ks) {
            arA = mfma16(afA[ks], wh[0][ks], arA);
            arB = mfma16(afB[ks], wh[0][ks], arB);
            azA = mfma16(afA[ks], wh[1][ks], azA);
            azB = mfma16(afB[ks], wh[1][ks], azB);
            anA = mfma16(afA[ks], wh[2][ks], anA);
            anB = mfma16(afB[ks], wh[2][ks], anB);
        }

        u16* ysA = ys_ws + (((size_t)a * T_ + t) * B_ + bA + quad * 4) * H_ + col;
        u16* ysB = ys_ws + (((size_t)a * T_ + t) * B_ + bB + quad * 4) * H_ + col;
#pragma unroll
        for (int r = 0; r < 4; ++r) {
            const float rgA = sigmoidf_(xrA[r] + arA[r]);
            const float rgB = sigmoidf_(xrB[r] + arB[r]);
            const float zgA = sigmoidf_(xzA[r] + azA[r]);
            const float zgB = sigmoidf_(xzB[r] + azB[r]);
            const float ngA = tanhf_(fmaf(rgA, anA[r] + bh, xnA[r]));
            const float ngB = tanhf_(fmaf(rgB, anB[r] + bh, xnB[r]));
            const float hA2 = fmaf(zgA, hmA[r] - ngA, ngA);
            const float hB2 = fmaf(zgB, hmB[r] - ngB, ngB);
            hmA[r] = hA2; hbA[r] = f2bc(hA2);
            hmB[r] = hB2; hbB[r] = f2bc(hB2);
            ysA[(size_t)r * H_] = hbA[r];
            ysB[(size_t)r * H_] = hbB[r];
        }
    }
#pragma unroll
    for (int r = 0; r < 4; ++r) {
        hT_out[((size_t)a * B_ + bA + quad * 4 + r) * H_ + col] = hmA[r];
        hT_out[((size_t)a * B_ + bB + quad * 4 + r) * H_ + col] = hmB[r];
    }
}

// ---------------- K3: actor/critic heads, weight-stationary ----------------
__global__ __launch_bounds__(512) void k_heads(
    const u16* __restrict__ ys_ws, const u16* __restrict__ wa1T, const u16* __restrict__ wc1T,
    const u16* __restrict__ h2T, const float* __restrict__ ba1, const float* __restrict__ bc1,
    const float* __restrict__ ba2, const float* __restrict__ bc2,
    float* __restrict__ mean_out, float* __restrict__ val_out) {
    __shared__ __align__(16) u16 ysl[16][136];
    __shared__ __align__(16) u16 al[2][16][136];
    const int a = blockIdx.y;
    const int wid = threadIdx.x >> 6, lane = threadIdx.x & 63;
    const int m = lane & 15, quad = lane >> 4;
    const int srow = threadIdx.x >> 5, schunk = threadIdx.x & 31;

    short8 wa[4], wc[4], h2f[4];
    {
        const u16* pa = wa1T + a * 16384 + (wid * 16 + m) * 128 + quad * 8;
        const u16* pc = wc1T + a * 16384 + (wid * 16 + m) * 128 + quad * 8;
        const u16* ph = h2T + a * 2048 + m * 128 + quad * 8;
#pragma unroll
        for (int ks = 0; ks < 4; ++ks) {
            wa[ks] = *(const short8*)(pa + ks * 32);
            wc[ks] = *(const short8*)(pc + ks * 32);
            h2f[ks] = *(const short8*)(ph + ks * 32);
        }
    }
    const float fa = ba1[a * 128 + wid * 16 + m];
    const float fc = bc1[a * 128 + wid * 16 + m];

    const u16* ysbase = ys_ws + ((size_t)a * 32768 + (size_t)blockIdx.x * 256 + srow) * 128 + schunk * 4;
    ushort4 pf = *(const ushort4*)(ysbase);

    for (int it = 0; it < 16; ++it) {
        *(ushort4*)&ysl[srow][schunk * 4] = pf;
        bar_lds();
        if (it + 1 < 16) pf = *(const ushort4*)(ysbase + (size_t)(it + 1) * 2048);

        short8 yf[4];
#pragma unroll
        for (int ks = 0; ks < 4; ++ks)
            yf[ks] = *(const short8*)&ysl[m][ks * 32 + quad * 8];
        f32x4 aa = f32x4{0.f, 0.f, 0.f, 0.f};
        f32x4 ac = f32x4{0.f, 0.f, 0.f, 0.f};
#pragma unroll
        for (int ks = 0; ks < 4; ++ks) {
            aa = mfma16(yf[ks], wa[ks], aa);
            ac = mfma16(yf[ks], wc[ks], ac);
        }
#pragma unroll
        for (int r = 0; r < 4; ++r) {
            al[0][quad * 4 + r][wid * 16 + m] = f2b(tanhf_(aa[r] + fa));
            al[1][quad * 4 + r][wid * 16 + m] = f2b(tanhf_(ac[r] + fc));
        }
        bar_lds();

        if (wid < 2) {
            short8 tf[4];
#pragma unroll
            for (int ks = 0; ks < 4; ++ks)
                tf[ks] = *(const short8*)&al[wid][m][ks * 32 + quad * 8];
            f32x4 tacc = f32x4{0.f, 0.f, 0.f, 0.f};
#pragma unroll
            for (int ks = 0; ks < 4; ++ks) tacc = mfma16(tf[ks], h2f[ks], tacc);
            const size_t R0 = (size_t)a * 32768 + (size_t)(blockIdx.x * 16 + it) * 16;
            if (wid == 0) {
                if (m < 8) {
                    const float bb = ba2[a * 8 + m];
#pragma unroll
                    for (int r = 0; r < 4; ++r)
                        mean_out[(R0 + quad * 4 + r) * 8 + m] = tacc[r] + bb;
                }
            } else {
                if (m == 8) {
                    const float bb = bc2[a];
#pragma unroll
                    for (int r = 0; r < 4; ++r)
                        val_out[R0 + quad * 4 + r] = tacc[r] + bb;
                }
            }
        }
    }
}

extern "C" void kernel_launch(void* const* d_in, const int* in_sizes, int n_in,
                              void* d_out, int out_size, void* d_ws, size_t ws_size,
                              hipStream_t stream) {
    const float* hstate = (const float*)d_in[0];
    const float* obs = (const float*)d_in[1];
    const float* We = (const float*)d_in[3];
    const float* be = (const float*)d_in[4];
    const float* Wi = (const float*)d_in[5];
    const float* bi = (const float*)d_in[6];
    const float* Wh = (const float*)d_in[7];
    const float* bhn = (const float*)d_in[8];
    const float* Wa1 = (const float*)d_in[9];
    const float* ba1 = (const float*)d_in[10];
    const float* Wa2 = (const float*)d_in[11];
    const float* ba2 = (const float*)d_in[12];
    const float* log_std = (const float*)d_in[13];
    const float* Wc1 = (const float*)d_in[14];
    const float* bc1 = (const float*)d_in[15];
    const float* Wc2 = (const float*)d_in[16];
    const float* bc2 = (const float*)d_in[17];
    const int* done = (const int*)d_in[18];

    float* out = (float*)d_out;
    float* hT_out = out;                    // (4,256,128)
    float* mean_out = out + 131072;         // (4,128,256,8)
    float* std_out = out + 1179648;         // (4,8)
    float* val_out = out + 1179680;         // (4,128,256)

    u16* ws = (u16*)d_ws;
    u16* xi = ws;
    u16* ys = xi + 50331648;
    u16* weT = ys + 16777216;
    u16* wiT = weT + 65536;
    u16* whT = wiT + 196608;
    u16* wa1T = whT + 196608;
    u16* wc1T = wa1T + 65536;
    u16* h2T = wc1T + 65536;

    hipLaunchKernelGGL(k_prep, dim3(2337), dim3(256), 0, stream,
                       We, Wi, Wh, Wa1, Wc1, Wa2, Wc2, log_std,
                       weT, wiT, whT, wa1T, wc1T, h2T, std_out);
    hipLaunchKernelGGL(k_embed_xi, dim3(128, 4), dim3(512), 0, stream,
                       obs, be, bi, weT, wiT, xi);
    hipLaunchKernelGGL(k_scan2, dim3(8, 4), dim3(512), 0, stream,
                       hstate, xi, whT, bhn, done, ys, hT_out);
    hipLaunchKernelGGL(k_heads, dim3(128, 4), dim3(512), 0, stream,
                       ys, wa1T, wc1T, h2T, ba1, bc1, ba2, bc2, mean_out, val_out);
}